// Round 12
// baseline (240.133 us; speedup 1.0000x reference)
//
#include <hip/hip_runtime.h>
#include <hip/hip_cooperative_groups.h>
#include <math.h>

namespace cg = cooperative_groups;

// Problem constants (B=16, H=512, W=512, fp32 in/out)
#define BB 16
#define HH 512
#define WW 512
#define NPIX (BB*HH*WW)   // 4194304
#define NWORDS 16         // 512 rows / 32 bits (full res)
#define HB 256            // half-res grid 256x256
#define HWORDS 8          // 256 block-rows / 32
#define NBLK 1024         // grid size (co-resident, cooperative)

// extract even bits 0,2,4,..,30 of x into low 16 bits
__device__ inline unsigned int even16(unsigned int x) {
  x &= 0x55555555u;
  x = (x | (x >> 1)) & 0x33333333u;
  x = (x | (x >> 2)) & 0x0F0F0F0Fu;
  x = (x | (x >> 4)) & 0x00FF00FFu;
  x = (x | (x >> 8)) & 0x0000FFFFu;
  return x;
}

// ---------------------------------------------------------------------------
// Single cooperative kernel, 1024 blocks x 256 threads (co-resident:
// launch_bounds(256,4) caps VGPR at 128 -> >=4 blocks/CU).
// Phase 1 (blocks 0..511): build full-res column bitmask (exact t bit-tests),
//   2x2-downsampled half-res bitmask, and half-res nearest-set-bit tables.
//   Block = (b, 16-col tile); thread (k,c) builds word k of column c.
// grid.sync()
// Phase 2 (all blocks): 4 sequential (b,R) half-res rows per block:
//   vertical EDT O(1)/col from tables -> LDS row -> horizontal min-plus
//   (scalar stride-1 chunked scan, wave-uniform exit) -> weights in LDS ->
//   per-pixel loss on full-res rows {2R,2R+1} (float4/uint4 loads).
//   Accumulate 4 loss terms across all 4 rows -> one partial set per block.
// grid.sync()
// Phase 3 (block 0): reduce 1024x4 partials -> scalar loss.
// No atomics, no explicit fences (grid.sync provides ordering).
// ---------------------------------------------------------------------------
__global__ __launch_bounds__(256, 4) void fused_kernel(
    const float* __restrict__ logits, const float* __restrict__ tg,
    unsigned int* __restrict__ mask, unsigned int* __restrict__ hmask,
    short* __restrict__ un_h, short* __restrict__ dn_h,
    float* __restrict__ partials, float* __restrict__ out) {
  cg::grid_group grid = cg::this_grid();

  __shared__ unsigned int smask[NWORDS][16];
  __shared__ unsigned int hsm[HWORDS][8];
  __shared__ __align__(16) float sraw[256 + HB + 256];
  __shared__ __align__(8) float sw[HB];
  __shared__ float wsum[4][4];
  float* sA = sraw + 256;

  int g = blockIdx.x;
  int tid = threadIdx.x;

  // ---------------- Phase 1: build (blocks 0..511) ----------------
  if (g < 512) {
    int b = g >> 5, wt = g & 31;     // 32 tiles of 16 px-cols
    int k = tid >> 4, c = tid & 15;  // word k (0..15), col c (0..15)
    int w = (wt << 4) + c;
    const float* p = tg + ((size_t)(b * HH + (k << 5))) * WW + w;
    unsigned int word = 0;
    #pragma unroll
    for (int r = 0; r < 32; ++r)
      word |= (p[(size_t)r * WW] > 0.f ? 1u : 0u) << r;
    smask[k][c] = word;
    mask[(b * NWORDS + k) * WW + w] = word;
    __syncthreads();
    if (tid < 64) {                  // half-res pack: 8 words x 8 block-cols
      int kp = tid >> 3, bcl = tid & 7;
      unsigned int wa = smask[2 * kp][2 * bcl] | smask[2 * kp][2 * bcl + 1];
      unsigned int wb = smask[2 * kp + 1][2 * bcl] | smask[2 * kp + 1][2 * bcl + 1];
      unsigned int hword =
          even16(wa | (wa >> 1)) | (even16(wb | (wb >> 1)) << 16);
      hsm[kp][bcl] = hword;
      hmask[(b * HWORDS + kp) * HB + (wt << 3) + bcl] = hword;
    }
    __syncthreads();
    if (tid < 8) {                   // suffix scan: first set block-row >= 32kp
      int bc = (wt << 3) + tid;
      int cur = 16000;
      un_h[(b * 9 + 8) * HB + bc] = (short)cur;
      #pragma unroll
      for (int kp = HWORDS - 1; kp >= 0; --kp) {
        unsigned int m = hsm[kp][tid];
        if (m) cur = (kp << 5) + (int)__builtin_ctz(m);
        un_h[(b * 9 + kp) * HB + bc] = (short)cur;
      }
    } else if (tid >= 64 && tid < 72) {  // prefix: last set block-row <= 32kp+31
      int tt = tid - 64;
      int bc = (wt << 3) + tt;
      int cur = -16000;
      dn_h[(b * 9 + 0) * HB + bc] = (short)cur;
      #pragma unroll
      for (int kp = 0; kp < HWORDS; ++kp) {
        unsigned int m = hsm[kp][tt];
        if (m) cur = (kp << 5) + 31 - (int)__builtin_clz(m);
        dn_h[(b * 9 + kp + 1) * HB + bc] = (short)cur;
      }
    }
  }

  grid.sync();

  // ---------------- Phase 2: EDT + loss, 4 (b,R) rows per block -----------
  int b2 = g >> 6;
  float acc_p = 0.f, acc_t = 0.f, acc_pt = 0.f, acc_pen = 0.f;

  #pragma unroll 1
  for (int j = 0; j < 4; ++j) {
    int R = ((g & 63) << 2) + j;     // half-res row 0..255

    // pads (never allowed to win the min)
    sraw[tid] = 3e12f;
    sraw[256 + HB + tid] = 3e12f;

    int k0 = R >> 5, pos = R & 31;   // block-uniform
    unsigned int pmask_lo = (1u << pos) - 1u;
    unsigned int pmask_le = pmask_lo | (1u << pos);

    unsigned int m0 = hmask[(b2 * HWORDS + k0) * HB + tid];
    int un_next = un_h[(b2 * 9 + k0 + 1) * HB + tid];
    int dn_prev = dn_h[(b2 * 9 + k0) * HB + tid];

    unsigned int upm  = m0 & ~pmask_lo;
    unsigned int lowm = m0 & pmask_le;
    int up  = upm  ? ((k0 << 5) + (int)__builtin_ctz(upm))       : un_next;
    int dnv = lowm ? ((k0 << 5) + 31 - (int)__builtin_clz(lowm)) : dn_prev;
    int bv = min(up - R, R - dnv);
    float dv = (bv > 255) ? 1e12f : (float)(bv * bv);
    sA[tid] = dv;
    __syncthreads();

    // horizontal min-plus: scalar stride-1 chunked scan, wave-uniform exit
    float best = dv;
    for (int o0 = 1; o0 < HB; o0 += 8) {
      if (__all((float)(o0 * o0) >= best)) break;
      #pragma unroll
      for (int u = 0; u < 8; ++u) {
        int o = o0 + u;
        best = fminf(best, fminf(sA[tid - o], sA[tid + o]) + (float)(o * o));
      }
    }
    // weight: physical d = 2*sqrt(best_blk); empty sample -> 0 (has_fg)
    sw[tid] = (best > 1e9f)
                  ? 0.f
                  : (1.f - __expf(-__builtin_amdgcn_sqrtf(best) * 0.04f));
    __syncthreads();

    // per-pixel loss on full-res rows {2R, 2R+1}
    int i = (R << 1) + (tid >> 7);
    int w0 = (tid & 127) << 2;
    float4 x4 = *(const float4*)&logits[((size_t)(b2 * HH + i)) * WW + w0];
    uint4 mw = *(const uint4*)&mask[(b2 * NWORDS + (i >> 5)) * WW + w0];
    float2 wv = *(const float2*)&sw[w0 >> 1];
    int bit = i & 31;

#define PX(XC, WC, MC)                                      \
    { float x = (XC);                                       \
      float tt = (float)(((MC) >> bit) & 1u);               \
      float e = __expf(-x);                                 \
      float pp = __builtin_amdgcn_rcpf(1.f + e);            \
      acc_p += pp; acc_t += tt; acc_pt += pp * tt;          \
      acc_pen += (WC) * pp * (1.f - tt); }
    PX(x4.x, wv.x, mw.x)
    PX(x4.y, wv.x, mw.y)
    PX(x4.z, wv.y, mw.z)
    PX(x4.w, wv.y, mw.w)
#undef PX
    __syncthreads();   // protect sraw/sw before next iteration overwrites
  }

  // block-level reduce of the 4 loss accumulators
  #pragma unroll
  for (int off = 32; off; off >>= 1) {
    acc_p  += __shfl_down(acc_p,  off);
    acc_t  += __shfl_down(acc_t,  off);
    acc_pt += __shfl_down(acc_pt, off);
    acc_pen += __shfl_down(acc_pen, off);
  }
  int wave = tid >> 6, lane = tid & 63;
  if (lane == 0) {
    wsum[wave][0] = acc_p; wsum[wave][1] = acc_t;
    wsum[wave][2] = acc_pt; wsum[wave][3] = acc_pen;
  }
  __syncthreads();
  if (tid == 0) {
    float r0 = 0.f, r1 = 0.f, r2 = 0.f, r3 = 0.f;
    #pragma unroll
    for (int wv2 = 0; wv2 < 4; ++wv2) {
      r0 += wsum[wv2][0]; r1 += wsum[wv2][1];
      r2 += wsum[wv2][2]; r3 += wsum[wv2][3];
    }
    partials[0 * NBLK + g] = r0;
    partials[1 * NBLK + g] = r1;
    partials[2 * NBLK + g] = r2;
    partials[3 * NBLK + g] = r3;
  }

  grid.sync();

  // ---------------- Phase 3: finalize (block 0) ----------------
  if (g == 0) {
    float a0 = 0.f, a1 = 0.f, a2 = 0.f, a3 = 0.f;
    for (int k = tid; k < NBLK; k += 256) {
      a0 += partials[0 * NBLK + k];
      a1 += partials[1 * NBLK + k];
      a2 += partials[2 * NBLK + k];
      a3 += partials[3 * NBLK + k];
    }
    #pragma unroll
    for (int off = 32; off; off >>= 1) {
      a0 += __shfl_down(a0, off);
      a1 += __shfl_down(a1, off);
      a2 += __shfl_down(a2, off);
      a3 += __shfl_down(a3, off);
    }
    if (lane == 0) {
      wsum[wave][0] = a0; wsum[wave][1] = a1;
      wsum[wave][2] = a2; wsum[wave][3] = a3;
    }
    __syncthreads();
    if (tid == 0) {
      float sp = 0.f, st = 0.f, inter = 0.f, pen = 0.f;
      #pragma unroll
      for (int wv2 = 0; wv2 < 4; ++wv2) {
        sp += wsum[wv2][0]; st += wsum[wv2][1];
        inter += wsum[wv2][2]; pen += wsum[wv2][3];
      }
      float uni = sp + st - inter;
      float iou_loss = 1.f - (inter + 1e-6f) / (uni + 1e-6f);
      float penalty = pen / (float)NPIX;
      out[0] = iou_loss + 0.5f * penalty;
    }
  }
}

extern "C" void kernel_launch(void* const* d_in, const int* in_sizes, int n_in,
                              void* d_out, int out_size, void* d_ws, size_t ws_size,
                              hipStream_t stream) {
  const float* logits = (const float*)d_in[0];
  const float* tg     = (const float*)d_in[1];
  char* base = (char*)d_ws;
  unsigned int* mask  = (unsigned int*)base;                 // 512 KB
  unsigned int* hmask = (unsigned int*)(base + 524288);      // 128 KB
  short* un_h = (short*)(base + 655360);                     // 72 KB
  short* dn_h = (short*)(base + 729088);                     // 72 KB
  float* partials = (float*)(base + 802816);                 // 16 KB
  float* out = (float*)d_out;

  void* args[] = {(void*)&logits, (void*)&tg, (void*)&mask, (void*)&hmask,
                  (void*)&un_h, (void*)&dn_h, (void*)&partials, (void*)&out};
  hipLaunchCooperativeKernel((const void*)fused_kernel, dim3(NBLK), dim3(256),
                             args, 0, stream);
}

// Round 13
// 21.834 us; speedup vs baseline: 10.9981x; 10.9981x over previous
//
#include <hip/hip_runtime.h>
#include <math.h>

// Problem constants (B=16, H=512, W=512, fp32 in/out)
#define BB 16
#define HH 512
#define WW 512
#define NPIX (BB*HH*WW)   // 4194304
#define NWORDS 16         // 512 rows / 32 bits (full res)
#define HB 256            // half-res grid 256x256
#define HWORDS 8          // 256 block-rows / 32
#define NBLK 1024         // edt_loss blocks = 16 images * 64

// extract even bits 0,2,4,..,30 of x into low 16 bits
__device__ inline unsigned int even16(unsigned int x) {
  x &= 0x55555555u;
  x = (x | (x >> 1)) & 0x33333333u;
  x = (x | (x >> 2)) & 0x0F0F0F0Fu;
  x = (x | (x >> 4)) & 0x00FF00FFu;
  x = (x | (x >> 8)) & 0x0000FFFFu;
  return x;
}

// ---------------------------------------------------------------------------
// Kernel A: full-res column bitmasks + 2x2-downsampled half-res bitmask +
// half-res nearest-set-bit tables. 256 blocks x 256 threads; block =
// (b, 32-col tile); thread (k, c2) builds words k of columns {2c2, 2c2+1}
// via 32 float2 loads (512B/wave-inst).
//   un_h[b][kp][bc]   = first set block-row >= 32kp    (slot 8 = +16000)
//   dn_h[b][kp+1][bc] = last  set block-row <= 32kp+31 (slot 0 = -16000)
// No atomics, no fences.
// ---------------------------------------------------------------------------
__global__ __launch_bounds__(256) void build_kernel(
    const float* __restrict__ tg, unsigned int* __restrict__ mask,
    unsigned int* __restrict__ hmask, short* __restrict__ un_h,
    short* __restrict__ dn_h) {
  __shared__ unsigned int smask[NWORDS][32];
  __shared__ unsigned int hsm[HWORDS][16];
  int wt = blockIdx.x & 15;          // 16 col-tiles of 32
  int b  = blockIdx.x >> 4;
  int c2 = threadIdx.x & 15;         // 0..15 -> columns {2c2, 2c2+1}
  int k  = threadIdx.x >> 4;         // 0..15
  int w  = (wt << 5) + (c2 << 1);
  const float* p = tg + ((size_t)(b * HH + (k << 5))) * WW + w;
  unsigned int w0 = 0, w1 = 0;
  #pragma unroll
  for (int r = 0; r < 32; ++r) {
    float2 v = *(const float2*)&p[(size_t)r * WW];
    w0 |= (v.x > 0.f ? 1u : 0u) << r;
    w1 |= (v.y > 0.f ? 1u : 0u) << r;
  }
  smask[k][(c2 << 1)] = w0;
  smask[k][(c2 << 1) + 1] = w1;
  *(uint2*)&mask[(b * NWORDS + k) * WW + w] = make_uint2(w0, w1);
  __syncthreads();
  int t = threadIdx.x;
  if (t < 128) {                     // half-res pack: 8 words x 16 block-cols
    int kp  = t >> 4;                // 0..7
    int bcl = t & 15;                // 0..15
    unsigned int wa = smask[2 * kp][2 * bcl] | smask[2 * kp][2 * bcl + 1];
    unsigned int wb = smask[2 * kp + 1][2 * bcl] | smask[2 * kp + 1][2 * bcl + 1];
    unsigned int hword = even16(wa | (wa >> 1)) | (even16(wb | (wb >> 1)) << 16);
    hsm[kp][bcl] = hword;
    hmask[(b * HWORDS + kp) * HB + (wt << 4) + bcl] = hword;
  }
  __syncthreads();
  if (t < 16) {                      // suffix scan: first set block-row >= 32kp
    int bc = (wt << 4) + t;
    int cur = 16000;
    un_h[(b * 9 + 8) * HB + bc] = (short)cur;
    #pragma unroll
    for (int kp = HWORDS - 1; kp >= 0; --kp) {
      unsigned int m = hsm[kp][t];
      if (m) cur = (kp << 5) + (int)__builtin_ctz(m);
      un_h[(b * 9 + kp) * HB + bc] = (short)cur;
    }
  } else if (t >= 64 && t < 80) {    // prefix scan: last set block-row <= 32kp+31
    int tt = t - 64;
    int bc = (wt << 4) + tt;
    int cur = -16000;
    dn_h[(b * 9 + 0) * HB + bc] = (short)cur;
    #pragma unroll
    for (int kp = 0; kp < HWORDS; ++kp) {
      unsigned int m = hsm[kp][tt];
      if (m) cur = (kp << 5) + 31 - (int)__builtin_clz(m);
      dn_h[(b * 9 + kp + 1) * HB + bc] = (short)cur;
    }
  }
}

// ---------------------------------------------------------------------------
// Kernel B: half-res EDT + per-pixel loss, 4 half-res rows per block.
// 1024 blocks x 256 threads; block (b = g>>6, Rbase = (g&63)*4).
// All 4 rows' logits/mask loads hoisted as NAMED scalars (rule #20) so HBM
// latency hides under the scans. One shuffle-reduce per block.
// No atomics, no fences.
// ---------------------------------------------------------------------------
__global__ __launch_bounds__(256) void edt_loss_kernel(
    const float* __restrict__ logits, const unsigned int* __restrict__ mask,
    const unsigned int* __restrict__ hmask, const short* __restrict__ un_h,
    const short* __restrict__ dn_h, float* __restrict__ partials) {
  __shared__ __align__(16) float sraw[256 + HB + 256];
  __shared__ __align__(8) float sw[HB];
  __shared__ float wsum[4][4];
  float* sA = sraw + 256;

  int g = blockIdx.x;
  int b = g >> 6, Rbase = (g & 63) << 2;
  int tid = threadIdx.x;

  // pads: once (never overwritten by row iterations)
  sraw[tid] = 3e12f;
  sraw[256 + HB + tid] = 3e12f;

  // hoisted per-row pixel loads: rows i_j = 2*(Rbase+j) + (tid>>7)
  int ir = tid >> 7;                 // 0 or 1: which of the row pair
  int wc = (tid & 127) << 2;         // 4 consecutive columns
  size_t lbase = ((size_t)(b * HH + (Rbase << 1) + ir)) * WW + wc;
  float4 x4_0 = *(const float4*)&logits[lbase];
  float4 x4_1 = *(const float4*)&logits[lbase + 2 * WW];
  float4 x4_2 = *(const float4*)&logits[lbase + 4 * WW];
  float4 x4_3 = *(const float4*)&logits[lbase + 6 * WW];
  uint4 mw_0 = *(const uint4*)&mask[(b * NWORDS + (((Rbase << 1) + ir) >> 5)) * WW + wc];
  uint4 mw_1 = *(const uint4*)&mask[(b * NWORDS + (((Rbase << 1) + 2 + ir) >> 5)) * WW + wc];
  uint4 mw_2 = *(const uint4*)&mask[(b * NWORDS + (((Rbase << 1) + 4 + ir) >> 5)) * WW + wc];
  uint4 mw_3 = *(const uint4*)&mask[(b * NWORDS + (((Rbase << 1) + 6 + ir) >> 5)) * WW + wc];

  float acc_p = 0.f, acc_t = 0.f, acc_pt = 0.f, acc_pen = 0.f;

#define PX(XC, WC, MC)                                      \
  { float x = (XC);                                         \
    float tt = (float)(((MC) >> bit) & 1u);                 \
    float e = __expf(-x);                                   \
    float pp = __builtin_amdgcn_rcpf(1.f + e);              \
    acc_p += pp; acc_t += tt; acc_pt += pp * tt;            \
    acc_pen += (WC) * pp * (1.f - tt); }

#define ROW_BODY(J, X4, MW)                                                   \
  {                                                                           \
    int R = Rbase + (J);                                                      \
    int k0 = R >> 5, pos = R & 31;                                            \
    unsigned int pmask_lo = (1u << pos) - 1u;                                 \
    unsigned int pmask_le = pmask_lo | (1u << pos);                           \
    unsigned int m0 = hmask[(b * HWORDS + k0) * HB + tid];                    \
    int un_next = un_h[(b * 9 + k0 + 1) * HB + tid];                          \
    int dn_prev = dn_h[(b * 9 + k0) * HB + tid];                              \
    unsigned int upm  = m0 & ~pmask_lo;                                       \
    unsigned int lowm = m0 & pmask_le;                                        \
    int up  = upm  ? ((k0 << 5) + (int)__builtin_ctz(upm))       : un_next;   \
    int dnv = lowm ? ((k0 << 5) + 31 - (int)__builtin_clz(lowm)) : dn_prev;   \
    int bv = min(up - R, R - dnv);                                            \
    float dv = (bv > 255) ? 1e12f : (float)(bv * bv);                         \
    sA[tid] = dv;                                                             \
    __syncthreads();                                                          \
    float best = dv;                                                          \
    for (int o0 = 1; o0 < HB; o0 += 8) {                                      \
      if (__all((float)(o0 * o0) >= best)) break;                             \
      _Pragma("unroll")                                                       \
      for (int u = 0; u < 8; ++u) {                                           \
        int o = o0 + u;                                                       \
        best = fminf(best, fminf(sA[tid - o], sA[tid + o]) + (float)(o * o)); \
      }                                                                       \
    }                                                                         \
    sw[tid] = (best > 1e9f)                                                   \
                  ? 0.f                                                       \
                  : (1.f - __expf(-__builtin_amdgcn_sqrtf(best) * 0.04f));    \
    __syncthreads();                                                          \
    int i = ((R) << 1) + ir;                                                  \
    int bit = i & 31;                                                         \
    float2 wv = *(const float2*)&sw[wc >> 1];                                 \
    PX(X4.x, wv.x, MW.x)                                                      \
    PX(X4.y, wv.x, MW.y)                                                      \
    PX(X4.z, wv.y, MW.z)                                                      \
    PX(X4.w, wv.y, MW.w)                                                      \
    __syncthreads();                                                          \
  }

  ROW_BODY(0, x4_0, mw_0)
  ROW_BODY(1, x4_1, mw_1)
  ROW_BODY(2, x4_2, mw_2)
  ROW_BODY(3, x4_3, mw_3)
#undef ROW_BODY
#undef PX

  // one block-level reduce for all 4 rows
  #pragma unroll
  for (int off = 32; off; off >>= 1) {
    acc_p  += __shfl_down(acc_p,  off);
    acc_t  += __shfl_down(acc_t,  off);
    acc_pt += __shfl_down(acc_pt, off);
    acc_pen += __shfl_down(acc_pen, off);
  }
  int wave = tid >> 6, lane = tid & 63;
  if (lane == 0) {
    wsum[wave][0] = acc_p; wsum[wave][1] = acc_t;
    wsum[wave][2] = acc_pt; wsum[wave][3] = acc_pen;
  }
  __syncthreads();
  if (tid == 0) {
    float r0 = 0.f, r1 = 0.f, r2 = 0.f, r3 = 0.f;
    #pragma unroll
    for (int wv2 = 0; wv2 < 4; ++wv2) {
      r0 += wsum[wv2][0]; r1 += wsum[wv2][1];
      r2 += wsum[wv2][2]; r3 += wsum[wv2][3];
    }
    partials[0 * NBLK + g] = r0;
    partials[1 * NBLK + g] = r1;
    partials[2 * NBLK + g] = r2;
    partials[3 * NBLK + g] = r3;
  }
}

// ---------------------------------------------------------------------------
// Kernel C: deterministic final reduce of 1024x4 partials + scalar loss.
// ---------------------------------------------------------------------------
__global__ __launch_bounds__(256) void finalize_kernel(
    const float* __restrict__ partials, float* __restrict__ out) {
  __shared__ float wsum[4][4];
  int tid = threadIdx.x;
  float a0 = 0.f, a1 = 0.f, a2 = 0.f, a3 = 0.f;
  for (int k = tid; k < NBLK; k += 256) {
    a0 += partials[0 * NBLK + k];
    a1 += partials[1 * NBLK + k];
    a2 += partials[2 * NBLK + k];
    a3 += partials[3 * NBLK + k];
  }
  #pragma unroll
  for (int off = 32; off; off >>= 1) {
    a0 += __shfl_down(a0, off);
    a1 += __shfl_down(a1, off);
    a2 += __shfl_down(a2, off);
    a3 += __shfl_down(a3, off);
  }
  int wave = tid >> 6, lane = tid & 63;
  if (lane == 0) {
    wsum[wave][0] = a0; wsum[wave][1] = a1;
    wsum[wave][2] = a2; wsum[wave][3] = a3;
  }
  __syncthreads();
  if (tid == 0) {
    float sp = 0.f, st = 0.f, inter = 0.f, pen = 0.f;
    #pragma unroll
    for (int wv = 0; wv < 4; ++wv) {
      sp += wsum[wv][0]; st += wsum[wv][1];
      inter += wsum[wv][2]; pen += wsum[wv][3];
    }
    float uni = sp + st - inter;
    float iou_loss = 1.f - (inter + 1e-6f) / (uni + 1e-6f);
    float penalty = pen / (float)NPIX;
    out[0] = iou_loss + 0.5f * penalty;
  }
}

extern "C" void kernel_launch(void* const* d_in, const int* in_sizes, int n_in,
                              void* d_out, int out_size, void* d_ws, size_t ws_size,
                              hipStream_t stream) {
  const float* logits = (const float*)d_in[0];
  const float* tg     = (const float*)d_in[1];
  char* base = (char*)d_ws;
  unsigned int* mask  = (unsigned int*)base;                 // 512 KB
  unsigned int* hmask = (unsigned int*)(base + 524288);      // 128 KB
  short* un_h = (short*)(base + 655360);                     // 72 KB
  short* dn_h = (short*)(base + 729088);                     // 72 KB
  float* partials = (float*)(base + 802816);                 // 16 KB
  float* out = (float*)d_out;

  hipLaunchKernelGGL(build_kernel, dim3(256), dim3(256), 0, stream,
                     tg, mask, hmask, un_h, dn_h);
  hipLaunchKernelGGL(edt_loss_kernel, dim3(NBLK), dim3(256), 0, stream,
                     logits, mask, hmask, un_h, dn_h, partials);
  hipLaunchKernelGGL(finalize_kernel, dim3(1), dim3(256), 0, stream,
                     partials, out);
}